// Round 6
// baseline (63.662 us; speedup 1.0000x reference)
//
#include <hip/hip_runtime.h>
#include <hip/hip_bf16.h>

typedef __bf16 bf16;
typedef __attribute__((ext_vector_type(4))) __bf16 bf16x4;
typedef __attribute__((ext_vector_type(8))) __bf16 bf16x8;
typedef __attribute__((ext_vector_type(4))) float f32x4;
typedef __attribute__((ext_vector_type(16))) float f32x16;

#define D_MODEL 1024
#define DK 128
#define LSEQ 2048
#define NB 4
// 1/sqrt(128) * log2(e): softmax runs in exp2 domain end-to-end
#define SCALE2 (0.08838834764831845f * 1.4426950408889634f)

#define GLD16(g, l) __builtin_amdgcn_global_load_lds(                       \
    (const __attribute__((address_space(1))) void*)(g),                     \
    (__attribute__((address_space(3))) void*)(l), 16, 0, 0)

// ---------------------------------------------------------------------------
// Kernel 0: transpose + bf16-convert weights. W[1024][128] f32 -> Wt[3][128][1024]
// ---------------------------------------------------------------------------
__global__ __launch_bounds__(256) void wt_kernel(
    const float* __restrict__ Wq, const float* __restrict__ Wk,
    const float* __restrict__ Wv, bf16* __restrict__ Wt)
{
    __shared__ bf16 tile[64][72];
    const float* W = (blockIdx.z == 0) ? Wq : (blockIdx.z == 1) ? Wk : Wv;
    int k0 = blockIdx.x * 64;
    int n0 = blockIdx.y * 64;
    int t  = threadIdx.x;
    #pragma unroll
    for (int i = 0; i < 16; ++i) {
        int idx = t + i * 256;
        int r = idx >> 6, c = idx & 63;
        tile[c][r] = (bf16)W[(size_t)(k0 + r) * DK + n0 + c];
    }
    __syncthreads();
    bf16* out = Wt + (size_t)blockIdx.z * DK * D_MODEL;
    #pragma unroll
    for (int i = 0; i < 16; ++i) {
        int idx = t + i * 256;
        int rr = idx >> 6, cc = idx & 63;
        out[(size_t)(n0 + rr) * D_MODEL + k0 + cc] = tile[rr][cc];
    }
}

// ---------------------------------------------------------------------------
// Kernel 1: QKV projection GEMM. X f32 x Wt bf16, M-tile 64, BK 64, 4 waves.
// Reg-staged double-buffer. Epilogue: Qs normal (pre-scaled), Kb and Vt
// written PRE-SWIZZLED (16B granule ^= token&7 within 128B groups) so attn's
// global_load_lds + ds_read_b128 is bank-conflict-free without LDS-side swizzle.
// ---------------------------------------------------------------------------
__global__ __launch_bounds__(256) void proj_kernel(
    const float* __restrict__ X, const bf16* __restrict__ Wt,
    bf16* __restrict__ Qs, bf16* __restrict__ Kb, bf16* __restrict__ Vt)
{
    __shared__ bf16 Xs[64][72];
    __shared__ bf16 Ws[128][72];
    int mt = blockIdx.x, mat = blockIdx.y;
    const bf16* W = Wt + (size_t)mat * DK * D_MODEL;
    int t = threadIdx.x;
    int wave = t >> 6, lane = t & 63;
    int lq = lane & 15, g = lane >> 4;
    int row0 = mt * 64;

    f32x4 acc[4][2];
    #pragma unroll
    for (int m = 0; m < 4; ++m)
        #pragma unroll
        for (int n = 0; n < 2; ++n) acc[m][n] = f32x4{0.f, 0.f, 0.f, 0.f};

    f32x4  rxf[4];
    bf16x8 rw[4];
    auto LOADR = [&](int k0) {
        #pragma unroll
        for (int i = 0; i < 4; ++i) {
            int u = t + i * 256, r = u >> 4, c4 = u & 15;
            rxf[i] = *reinterpret_cast<const f32x4*>(
                &X[(size_t)(row0 + r) * D_MODEL + k0 + c4 * 4]);
        }
        #pragma unroll
        for (int i = 0; i < 4; ++i) {
            int u = t + i * 256, r = u >> 3, c8 = u & 7;
            rw[i] = *reinterpret_cast<const bf16x8*>(
                &W[(size_t)r * D_MODEL + k0 + c8 * 8]);
        }
    };
    auto STORER = [&]() {
        #pragma unroll
        for (int i = 0; i < 4; ++i) {
            int u = t + i * 256, r = u >> 4, c4 = u & 15;
            bf16x4 h;
            h[0]=(bf16)rxf[i][0]; h[1]=(bf16)rxf[i][1];
            h[2]=(bf16)rxf[i][2]; h[3]=(bf16)rxf[i][3];
            *reinterpret_cast<bf16x4*>(&Xs[r][c4 * 4]) = h;
        }
        #pragma unroll
        for (int i = 0; i < 4; ++i) {
            int u = t + i * 256, r = u >> 3, c8 = u & 7;
            *reinterpret_cast<bf16x8*>(&Ws[r][c8 * 8]) = rw[i];
        }
    };

    LOADR(0);
    for (int ks = 0; ks < 16; ++ks) {
        __syncthreads();
        STORER();
        if (ks + 1 < 16) LOADR((ks + 1) * 64);
        __syncthreads();
        #pragma unroll
        for (int kk = 0; kk < 2; ++kk) {
            bf16x8 a[4];
            #pragma unroll
            for (int mr = 0; mr < 4; ++mr)
                a[mr] = *reinterpret_cast<const bf16x8*>(&Xs[mr * 16 + lq][kk * 32 + g * 8]);
            #pragma unroll
            for (int n = 0; n < 2; ++n) {
                bf16x8 bfr = *reinterpret_cast<const bf16x8*>(
                    &Ws[wave * 32 + n * 16 + lq][kk * 32 + g * 8]);
                #pragma unroll
                for (int mr = 0; mr < 4; ++mr)
                    acc[mr][n] = __builtin_amdgcn_mfma_f32_16x16x32_bf16(a[mr], bfr, acc[mr][n], 0, 0, 0);
            }
        }
    }
    #pragma unroll
    for (int mr = 0; mr < 4; ++mr) {
        int orow = row0 + mr * 16 + g * 4;
        #pragma unroll
        for (int n = 0; n < 2; ++n) {
            int col = wave * 32 + n * 16 + lq;
            if (mat == 0) {
                #pragma unroll
                for (int r = 0; r < 4; ++r)
                    Qs[(size_t)(orow + r) * DK + col] = (bf16)(acc[mr][n][r] * SCALE2);
            } else if (mat == 1) {
                int colg = col >> 3, cre = col & 7;
                #pragma unroll
                for (int r = 0; r < 4; ++r) {
                    int row = orow + r;    // token (kv)
                    Kb[(size_t)row * DK + ((colg ^ (row & 7)) << 3) + cre]
                        = (bf16)acc[mr][n][r];
                }
            } else {
                int bb  = orow >> 11;
                int kv0 = orow & 2047;     // multiple of 4; 4-span stays in granule
                int gv  = ((kv0 & 63) >> 3) ^ (col & 7);   // swizzle key = d&7
                bf16x4 h;
                h[0]=(bf16)acc[mr][n][0]; h[1]=(bf16)acc[mr][n][1];
                h[2]=(bf16)acc[mr][n][2]; h[3]=(bf16)acc[mr][n][3];
                *reinterpret_cast<bf16x4*>(
                    &Vt[((size_t)bb * DK + col) * LSEQ + (kv0 & ~63) + (gv << 3) + (kv0 & 7)]) = h;
            }
        }
    }
}

// ---------------------------------------------------------------------------
// Kernel 2: split-KV causal flash attention. 128-thr / 2-wave blocks,
// wave = 32 q-rows, 32x32x16 MFMA. K/V double-buffered in LDS via
// global_load_lds (sources pre-swizzled in global => conflict-free b128 reads
// with granule ^= row&7). One __syncthreads per tile = the pipeline wait.
// ---------------------------------------------------------------------------
__global__ __launch_bounds__(128, 2) void attn_kernel(
    const bf16* __restrict__ Qs, const bf16* __restrict__ Kb,
    const bf16* __restrict__ Vt, float* __restrict__ Zp,
    float* __restrict__ Mp, float* __restrict__ Lp,
    float* __restrict__ Out, int S, int direct)
{
    __shared__ __align__(16) bf16 Ks[2][64][128];
    __shared__ __align__(16) bf16 Vs[2][128][64];
    __shared__ __align__(16) bf16 Pw[2][32][72];

    int bid = blockIdx.x;
    int b, qblk, s;
    if (S == 4) {
        int xcd = bid & 7, n = bid >> 3;      // n in [0,64)
        b = xcd >> 1;                         // XCD-pinned batch (KV L2-fit)
        int half = n >> 5, qraw = n & 31;
        qblk = half ? (31 - qraw) : qraw;     // complementary (q,31-q) pairing
        s = ((xcd & 1) << 1) | half;
    } else {
        b = bid / (S * 32);
        int rem = bid % (S * 32);
        qblk = rem & 31;
        s = rem >> 5;
    }
    int t = threadIdx.x;
    int wave = t >> 6, lane = t & 63;
    int l31 = lane & 31, hi = lane >> 5;
    int qg  = qblk * 64 + wave * 32 + l31;    // this lane's q row
    int swz = l31 & 7;

    int nt  = qblk + 1;                       // 64-kv tiles, same for both waves
    int cpt = (nt + S - 1) / S;
    int t0  = s * cpt;
    int t1  = min(t0 + cpt, nt);

    const bf16* Kbase = Kb + (size_t)b * LSEQ * DK;
    const bf16* Vbase = Vt + (size_t)b * DK * LSEQ;

    // Q fragments (B-operand): col=l31 (q), k=(hi)*8+j per 16-chunk
    const bf16* Qrow = Qs + ((size_t)b * LSEQ + qg) * DK;
    bf16x8 qf[8];
    #pragma unroll
    for (int ks = 0; ks < 8; ++ks)
        qf[ks] = *reinterpret_cast<const bf16x8*>(&Qrow[ks * 16 + hi * 8]);

    f32x16 z[4];
    #pragma unroll
    for (int db = 0; db < 4; ++db)
        #pragma unroll
        for (int r = 0; r < 16; ++r) z[db][r] = 0.f;
    float mrun = -3.0e38f, lrun = 0.f;

    auto STAGE = [&](int buf, int ti) {
        int kvb = ti * 64;
        // K tile: 64 rows x 256B, contiguous 16KB in (pre-swizzled) Kb
        const char* kg = (const char*)(Kbase + (size_t)kvb * DK) + t * 16;
        char* kl = (char*)(&Ks[buf][0][0]) + t * 16;
        #pragma unroll
        for (int i = 0; i < 8; ++i)
            GLD16(kg + i * 2048, kl + i * 2048);
        // V tile: 128 rows x 128B strips, stride LSEQ*2
        const char* vg = (const char*)Vbase + (size_t)(t >> 3) * (LSEQ * 2)
                       + (size_t)kvb * 2 + (t & 7) * 16;
        char* vl = (char*)(&Vs[buf][0][0]) + t * 16;
        #pragma unroll
        for (int i = 0; i < 8; ++i)
            GLD16(vg + (size_t)i * 16 * (LSEQ * 2), vl + i * 2048);
    };

    if (t0 < t1) {
        STAGE(0, t0);
        int cur = 0;
        for (int ti = t0; ti < t1; ++ti) {
            __syncthreads();               // implicit vmcnt(0): buf[cur] ready
            if (ti + 1 < t1) STAGE(cur ^ 1, ti + 1);   // lands during compute
            int kvb = ti * 64;

            f32x16 sc[2];
            #pragma unroll
            for (int jj = 0; jj < 2; ++jj)
                #pragma unroll
                for (int r = 0; r < 16; ++r) sc[jj][r] = 0.f;

            __builtin_amdgcn_s_setprio(1);
            #pragma unroll
            for (int jj = 0; jj < 2; ++jj) {
                const char* kr = (const char*)&Ks[cur][jj * 32 + l31][0];
                #pragma unroll
                for (int ks = 0; ks < 8; ++ks) {
                    bf16x8 a = *reinterpret_cast<const bf16x8*>(
                        kr + (((2 * ks + hi) ^ swz) << 4));
                    sc[jj] = __builtin_amdgcn_mfma_f32_32x32x16_bf16(a, qf[ks], sc[jj], 0, 0, 0);
                }
            }
            __builtin_amdgcn_s_setprio(0);

            // mask (diagonal tile only) + row max; C row = (r&3)+8*(r>>2)+4*hi
            float mt = -3.0e38f;
            if (ti == nt - 1) {
                #pragma unroll
                for (int jj = 0; jj < 2; ++jj)
                    #pragma unroll
                    for (int r = 0; r < 16; ++r) {
                        int kv0 = kvb + jj * 32 + (r & 3) + 8 * (r >> 2) + 4 * hi;
                        float v = (kv0 <= qg) ? sc[jj][r] : -3.0e38f;
                        sc[jj][r] = v;
                        mt = fmaxf(mt, v);
                    }
            } else {
                #pragma unroll
                for (int jj = 0; jj < 2; ++jj)
                    #pragma unroll
                    for (int r = 0; r < 16; ++r) mt = fmaxf(mt, sc[jj][r]);
            }
            mt = fmaxf(mt, __shfl_xor(mt, 32));
            if (!__all(mt <= mrun)) {
                float mnew  = fmaxf(mrun, mt);
                float alpha = exp2f(mrun - mnew);
                lrun *= alpha;
                #pragma unroll
                for (int db = 0; db < 4; ++db)
                    #pragma unroll
                    for (int r = 0; r < 16; ++r) z[db][r] *= alpha;
                mrun = mnew;
            }
            float psum = 0.f;
            #pragma unroll
            for (int jj = 0; jj < 2; ++jj) {
                #pragma unroll
                for (int rq = 0; rq < 4; ++rq) {
                    bf16x4 pb;
                    #pragma unroll
                    for (int r = 0; r < 4; ++r) {
                        float e = exp2f(sc[jj][rq * 4 + r] - mrun);
                        psum += e;
                        pb[r] = (bf16)e;
                    }
                    *reinterpret_cast<bf16x4*>(
                        &Pw[wave][l31][jj * 32 + rq * 8 + hi * 4]) = pb;
                }
            }
            psum += __shfl_xor(psum, 32);
            lrun += psum;

            __builtin_amdgcn_s_setprio(1);
            #pragma unroll
            for (int kc = 0; kc < 4; ++kc) {
                bf16x8 pb = *reinterpret_cast<const bf16x8*>(
                    &Pw[wave][l31][kc * 16 + hi * 8]);
                #pragma unroll
                for (int db = 0; db < 4; ++db) {
                    bf16x8 a = *reinterpret_cast<const bf16x8*>(
                        (const char*)&Vs[cur][db * 32 + l31][0]
                        + (((2 * kc + hi) ^ swz) << 4));
                    z[db] = __builtin_amdgcn_mfma_f32_32x32x16_bf16(a, pb, z[db], 0, 0, 0);
                }
            }
            __builtin_amdgcn_s_setprio(0);
            cur ^= 1;
        }
    }

    // Z^T: col=q (lane), row d = db*32 + (r&3)+8*(r>>2)+4*hi
    if (direct) {
        float inv = 1.f / lrun;
        float* orow = Out + ((size_t)b * LSEQ + qg) * DK;
        #pragma unroll
        for (int db = 0; db < 4; ++db)
            #pragma unroll
            for (int rq = 0; rq < 4; ++rq) {
                f32x4 v;
                v[0] = z[db][rq*4+0] * inv; v[1] = z[db][rq*4+1] * inv;
                v[2] = z[db][rq*4+2] * inv; v[3] = z[db][rq*4+3] * inv;
                *reinterpret_cast<f32x4*>(&orow[db * 32 + rq * 8 + hi * 4]) = v;
            }
    } else {
        size_t T = (size_t)(b * 32 + qblk) * S + s;
        float* zp = Zp + T * (64 * 128) + (size_t)(wave * 32 + l31) * 128;
        #pragma unroll
        for (int db = 0; db < 4; ++db)
            #pragma unroll
            for (int rq = 0; rq < 4; ++rq) {
                f32x4 v;
                v[0] = z[db][rq*4+0]; v[1] = z[db][rq*4+1];
                v[2] = z[db][rq*4+2]; v[3] = z[db][rq*4+3];
                *reinterpret_cast<f32x4*>(&zp[db * 32 + rq * 8 + hi * 4]) = v;
            }
        if (hi == 0) {
            Mp[T * 64 + wave * 32 + l31] = mrun;
            Lp[T * 64 + wave * 32 + l31] = lrun;
        }
    }
}

// ---------------------------------------------------------------------------
// Kernel 3: merge split-KV partials. One block per (64-row tile, b), 256 thr.
// ---------------------------------------------------------------------------
__global__ __launch_bounds__(256) void combine_kernel(
    const float* __restrict__ Zp, const float* __restrict__ Mp,
    const float* __restrict__ Lp, float* __restrict__ Out, int S)
{
    int qt = blockIdx.x, b = blockIdx.y;
    int t  = threadIdx.x;
    int r  = t & 63;
    int dc = t >> 6;                 // 4 chunks of 32 d
    size_t Tbase = (size_t)(b * 32 + qt) * S;

    float m = -3.0e38f;
    for (int s = 0; s < S; ++s)
        m = fmaxf(m, Mp[(Tbase + s) * 64 + r]);

    float L = 0.f;
    f32x4 a[8];
    #pragma unroll
    for (int j = 0; j < 8; ++j) a[j] = f32x4{0.f, 0.f, 0.f, 0.f};
    for (int s = 0; s < S; ++s) {
        float mm = Mp[(Tbase + s) * 64 + r];
        float w  = exp2f(mm - m);
        L += w * Lp[(Tbase + s) * 64 + r];
        const float* zp = Zp + (Tbase + s) * 8192 + (size_t)r * 128 + dc * 32;
        #pragma unroll
        for (int j = 0; j < 8; ++j) {
            f32x4 v = *reinterpret_cast<const f32x4*>(&zp[j * 4]);
            a[j][0] += w * v[0]; a[j][1] += w * v[1];
            a[j][2] += w * v[2]; a[j][3] += w * v[3];
        }
    }
    float inv = 1.f / L;
    float* orow = Out + ((size_t)b * LSEQ + qt * 64 + r) * DK + dc * 32;
    #pragma unroll
    for (int j = 0; j < 8; ++j) {
        f32x4 o;
        o[0]=a[j][0]*inv; o[1]=a[j][1]*inv; o[2]=a[j][2]*inv; o[3]=a[j][3]*inv;
        *reinterpret_cast<f32x4*>(&orow[j * 4]) = o;
    }
}

// ---------------------------------------------------------------------------
extern "C" void kernel_launch(void* const* d_in, const int* in_sizes, int n_in,
                              void* d_out, int out_size, void* d_ws, size_t ws_size,
                              hipStream_t stream)
{
    const float* X  = (const float*)d_in[0];
    const float* Wq = (const float*)d_in[1];
    const float* Wk = (const float*)d_in[2];
    const float* Wv = (const float*)d_in[3];
    float* Out = (float*)d_out;

    char* ws = (char*)d_ws;
    // layout: Wt @0 (768KB) ; Qs @1MB ; Kb @3MB ; Vt @5MB ; partials @7MB
    bf16* Wt = (bf16*)(ws);
    bf16* Qs = (bf16*)(ws + ((size_t)1 << 20));
    bf16* Kb = (bf16*)(ws + ((size_t)3 << 20));
    bf16* Vt = (bf16*)(ws + ((size_t)5 << 20));
    size_t base = (size_t)7 << 20;

    auto need = [](int S) -> size_t {
        return ((size_t)7 << 20)
             + (size_t)S * ((size_t)NB * 32 * 64 * 128 * 4)      // Zp
             + (size_t)S * 2 * ((size_t)NB * 32 * 64 * 4);       // Mp, Lp
    };
    int S = 1;
    if      (ws_size >= need(4)) S = 4;
    else if (ws_size >= need(2)) S = 2;

    float* Zp = (float*)(ws + base);
    float* Mp = (float*)(ws + base + (size_t)S * NB * 32 * 64 * 128 * 4);
    float* Lp = (float*)(ws + base + (size_t)S * NB * 32 * 64 * 128 * 4
                                   + (size_t)S * NB * 32 * 64 * 4);

    hipLaunchKernelGGL(wt_kernel,   dim3(16, 2, 3), dim3(256), 0, stream, Wq, Wk, Wv, Wt);
    hipLaunchKernelGGL(proj_kernel, dim3(128, 3),   dim3(256), 0, stream, X, Wt, Qs, Kb, Vt);
    hipLaunchKernelGGL(attn_kernel, dim3(S * 32 * NB), dim3(128), 0, stream,
                       Qs, Kb, Vt, Zp, Mp, Lp, Out, S, (S == 1) ? 1 : 0);
    if (S > 1)
        hipLaunchKernelGGL(combine_kernel, dim3(32, NB), dim3(256), 0, stream,
                           Zp, Mp, Lp, Out, S);
}